// Round 1
// baseline (11908.511 us; speedup 1.0000x reference)
//
#include <hip/hip_runtime.h>
#include <math.h>

#define B 32
#define S 41
#define T 41
#define H 1024
#define V 16384
#define BH (B*H)

__device__ __forceinline__ float fast_sigmoid(float x){ return 1.f/(1.f + __expf(-x)); }
__device__ __forceinline__ float fast_tanh(float x){
  float e = __expf(-2.f*fabsf(x));
  float r = (1.f - e)/(1.f + e);
  return copysignf(r, x);
}

// ---------------- init: h = encoder_hidden[0], c = 0 ----------------
__global__ __launch_bounds__(256) void k_init(const float* __restrict__ eh,
                                              float* __restrict__ h, float* __restrict__ c){
  int i = blockIdx.x*256 + threadIdx.x;
  h[i] = eh[i]; c[i] = 0.f;
}

// ---------------- generic f32 GEMM: C[m][n] = sum_k A[m][k]*W[n][k] + bias[n] ----------------
// 128x128 tile, BK=16, 256 threads, 8x8 per-thread. N,K multiples of 128/16; M guarded.
__global__ __launch_bounds__(256) void k_gemm(const float* __restrict__ A,
    const float* __restrict__ W, const float* __restrict__ bias,
    float* __restrict__ C, int M, int N, int K)
{
  __shared__ float As[16][128];
  __shared__ float Ws[16][128];
  const int m0 = blockIdx.x*128, n0 = blockIdx.y*128;
  const int tid = threadIdx.x;
  const int r = tid & 127, kq = tid >> 7;          // kq in {0,1}
  const int tm = (tid >> 4)*8, tn = (tid & 15)*8;
  float acc[8][8] = {};
  const float* a_base = A + (size_t)(m0 + r)*K;
  const float* w_base = W + (size_t)(n0 + r)*K;
  const bool arow_ok = (m0 + r) < M;
  for (int k0 = 0; k0 < K; k0 += 16) {
    float4 av0 = {0,0,0,0}, av1 = {0,0,0,0};
    if (arow_ok) {
      av0 = *(const float4*)(a_base + k0 + kq*4);
      av1 = *(const float4*)(a_base + k0 + 8 + kq*4);
    }
    float4 wv0 = *(const float4*)(w_base + k0 + kq*4);
    float4 wv1 = *(const float4*)(w_base + k0 + 8 + kq*4);
    __syncthreads();
    {
      int kk = kq*4;
      As[kk+0][r]=av0.x; As[kk+1][r]=av0.y; As[kk+2][r]=av0.z; As[kk+3][r]=av0.w;
      As[kk+8][r]=av1.x; As[kk+9][r]=av1.y; As[kk+10][r]=av1.z; As[kk+11][r]=av1.w;
      Ws[kk+0][r]=wv0.x; Ws[kk+1][r]=wv0.y; Ws[kk+2][r]=wv0.z; Ws[kk+3][r]=wv0.w;
      Ws[kk+8][r]=wv1.x; Ws[kk+9][r]=wv1.y; Ws[kk+10][r]=wv1.z; Ws[kk+11][r]=wv1.w;
    }
    __syncthreads();
    #pragma unroll
    for (int k=0;k<16;k++){
      float a[8], w[8];
      *(float4*)&a[0] = *(const float4*)&As[k][tm];
      *(float4*)&a[4] = *(const float4*)&As[k][tm+4];
      *(float4*)&w[0] = *(const float4*)&Ws[k][tn];
      *(float4*)&w[4] = *(const float4*)&Ws[k][tn+4];
      #pragma unroll
      for (int i=0;i<8;i++)
        #pragma unroll
        for (int j=0;j<8;j++)
          acc[i][j] = fmaf(a[i], w[j], acc[i][j]);
    }
  }
  #pragma unroll
  for (int i=0;i<8;i++){
    int m = m0 + tm + i;
    if (m >= M) break;
    float* crow = C + (size_t)m*N + n0 + tn;
    #pragma unroll
    for (int j=0;j<8;j++) crow[j] = acc[i][j] + bias[n0 + tn + j];
  }
}

// ---------------- per-step query: q[b][g] = h[b]·Wq[g] + bq[g] ----------------
__global__ __launch_bounds__(256) void k_query(const float* __restrict__ h,
    const float* __restrict__ Wq, const float* __restrict__ bq, float* __restrict__ q)
{
  int idx = blockIdx.x*256 + threadIdx.x;   // 32768
  int b = idx & 31, g = idx >> 5;
  const float4* hv = (const float4*)(h + b*H);
  const float4* wv = (const float4*)(Wq + (size_t)g*H);
  float s = 0.f;
  #pragma unroll 8
  for (int k=0;k<H/4;k++){
    float4 a=hv[k], w=wv[k];
    s = fmaf(a.x,w.x,s); s = fmaf(a.y,w.y,s); s = fmaf(a.z,w.z,s); s = fmaf(a.w,w.w,s);
  }
  q[b*H + g] = s + bq[g];
}

// ---------------- per-step attention: scores -> softmax -> ctx; writes xi=[x|ctx], attn ----------------
__global__ __launch_bounds__(256) void k_attn(
    const float* __restrict__ q,     // [B][H]
    const float* __restrict__ keys,  // [B][S][H]
    const float* __restrict__ enc,   // [B][S][H]
    const float* __restrict__ Vw, const float* __restrict__ bV,
    const float* __restrict__ emb,   // [V][H]
    const int*  __restrict__ tgt,    // [B][T]
    int t,
    float* __restrict__ xi,          // [B][2H]
    float* __restrict__ attn_out)    // [B][T][S]
{
  const int b = blockIdx.x;
  const int tid = threadIdx.x;
  const int lane = tid & 63, wave = tid >> 6;
  __shared__ float w_sh[S];

  // scores: each wave handles s = wave, wave+4, ...
  const float4* q4 = (const float4*)(q + b*H);
  const float4* v4 = (const float4*)Vw;
  for (int s = wave; s < S; s += 4) {
    const float4* k4 = (const float4*)(keys + ((size_t)b*S + s)*H);
    float acc = 0.f;
    #pragma unroll
    for (int j=0;j<4;j++){
      int i = lane + 64*j;
      float4 qv = q4[i], kv = k4[i], vv = v4[i];
      acc += fast_tanh(qv.x+kv.x)*vv.x;
      acc += fast_tanh(qv.y+kv.y)*vv.y;
      acc += fast_tanh(qv.z+kv.z)*vv.z;
      acc += fast_tanh(qv.w+kv.w)*vv.w;
    }
    #pragma unroll
    for (int off=32; off>0; off>>=1) acc += __shfl_down(acc, off);
    if (lane==0) w_sh[s] = acc + bV[0];
  }
  __syncthreads();
  // softmax over 41 entries (single wave)
  if (tid < 64) {
    float val = (tid < S) ? w_sh[tid] : -1e30f;
    float m = val;
    #pragma unroll
    for (int off=32; off>0; off>>=1) m = fmaxf(m, __shfl_xor(m, off));
    float e = (tid < S) ? __expf(val - m) : 0.f;
    float ssum = e;
    #pragma unroll
    for (int off=32; off>0; off>>=1) ssum += __shfl_xor(ssum, off);
    float w = e / ssum;
    if (tid < S) {
      attn_out[((size_t)b*T + t)*S + tid] = w;
    }
    __syncthreads();
    if (tid < S) w_sh[tid] = w;
  } else {
    __syncthreads();
  }
  __syncthreads();
  // ctx + embedding gather; each thread owns 4 consecutive h
  {
    int hbase = tid*4;
    float4 cx = {0,0,0,0};
    for (int s=0;s<S;s++){
      float w = w_sh[s];
      float4 ev = *(const float4*)(enc + ((size_t)b*S + s)*H + hbase);
      cx.x = fmaf(w, ev.x, cx.x); cx.y = fmaf(w, ev.y, cx.y);
      cx.z = fmaf(w, ev.z, cx.z); cx.w = fmaf(w, ev.w, cx.w);
    }
    *(float4*)(xi + (size_t)b*2*H + H + hbase) = cx;
    int tok = (t==0) ? 0 : tgt[b*T + (t-1)];
    *(float4*)(xi + (size_t)b*2*H + hbase) = *(const float4*)(emb + (size_t)tok*H + hbase);
  }
}

// ---------------- per-step gates: gates[b][n] = xi[b]·Wih[n] + h[b]·Whh[n] + bih[n]+bhh[n] ----------------
__global__ __launch_bounds__(256) void k_gates(const float* __restrict__ xi,
    const float* __restrict__ h, const float* __restrict__ Wih, const float* __restrict__ Whh,
    const float* __restrict__ bih, const float* __restrict__ bhh, float* __restrict__ gates)
{
  int idx = blockIdx.x*256 + threadIdx.x;  // 32*4096
  int b = idx & 31, n = idx >> 5;
  float s = 0.f;
  {
    const float4* x4 = (const float4*)(xi + (size_t)b*2*H);
    const float4* w4 = (const float4*)(Wih + (size_t)n*2*H);
    #pragma unroll 4
    for (int k=0;k<(2*H)/4;k++){
      float4 a=x4[k], w=w4[k];
      s = fmaf(a.x,w.x,s); s = fmaf(a.y,w.y,s); s = fmaf(a.z,w.z,s); s = fmaf(a.w,w.w,s);
    }
  }
  {
    const float4* h4 = (const float4*)(h + (size_t)b*H);
    const float4* w4 = (const float4*)(Whh + (size_t)n*H);
    #pragma unroll 4
    for (int k=0;k<H/4;k++){
      float4 a=h4[k], w=w4[k];
      s = fmaf(a.x,w.x,s); s = fmaf(a.y,w.y,s); s = fmaf(a.z,w.z,s); s = fmaf(a.w,w.w,s);
    }
  }
  gates[(size_t)b*4*H + n] = s + bih[n] + bhh[n];
}

// ---------------- per-step LSTM update ----------------
__global__ __launch_bounds__(256) void k_lstm(const float* __restrict__ gates,
    float* __restrict__ hcur, float* __restrict__ ccur, float* __restrict__ hhist, int t)
{
  int idx = blockIdx.x*256 + threadIdx.x;  // 32768
  int b = idx >> 10, m = idx & 1023;
  const float* g = gates + (size_t)b*4*H;
  float ig = fast_sigmoid(g[m]);
  float fg = fast_sigmoid(g[H + m]);
  float gg = fast_tanh(g[2*H + m]);
  float og = fast_sigmoid(g[3*H + m]);
  float c = fg * ccur[idx] + ig * gg;
  float hn = og * fast_tanh(c);
  ccur[idx] = c;
  hcur[idx] = hn;
  hhist[((size_t)b*T + t)*H + m] = hn;   // row b*T+t matches decoder_outputs row
}

// ---------------- log_softmax in-place over rows of 16384 (single pass, regs) ----------------
__global__ __launch_bounds__(256) void k_logsm(float* __restrict__ p_all)
{
  float* p = p_all + (size_t)blockIdx.x * V;
  const int tid = threadIdx.x;
  const int lane = tid & 63, wave = tid >> 6;
  __shared__ float red[4];
  float4 v[16];
  float m = -1e30f;
  #pragma unroll
  for (int j=0;j<16;j++){
    v[j] = *(const float4*)(p + 4*(tid + 256*j));
    m = fmaxf(m, fmaxf(fmaxf(v[j].x, v[j].y), fmaxf(v[j].z, v[j].w)));
  }
  #pragma unroll
  for (int off=32; off>0; off>>=1) m = fmaxf(m, __shfl_xor(m, off));
  if (lane==0) red[wave] = m;
  __syncthreads();
  m = fmaxf(fmaxf(red[0], red[1]), fmaxf(red[2], red[3]));
  float ssum = 0.f;
  #pragma unroll
  for (int j=0;j<16;j++){
    ssum += __expf(v[j].x - m) + __expf(v[j].y - m) + __expf(v[j].z - m) + __expf(v[j].w - m);
  }
  #pragma unroll
  for (int off=32; off>0; off>>=1) ssum += __shfl_xor(ssum, off);
  __syncthreads();
  if (lane==0) red[wave] = ssum;
  __syncthreads();
  float lse = m + __logf(red[0] + red[1] + red[2] + red[3]);
  #pragma unroll
  for (int j=0;j<16;j++){
    float4 o; o.x = v[j].x - lse; o.y = v[j].y - lse; o.z = v[j].z - lse; o.w = v[j].w - lse;
    *(float4*)(p + 4*(tid + 256*j)) = o;
  }
}

// ---------------- final h/c copy ----------------
__global__ __launch_bounds__(256) void k_copyhc(const float* __restrict__ h, const float* __restrict__ c,
                                                float* __restrict__ oh, float* __restrict__ oc)
{
  int i = blockIdx.x*256 + threadIdx.x;
  oh[i] = h[i]; oc[i] = c[i];
}

extern "C" void kernel_launch(void* const* d_in, const int* in_sizes, int n_in,
                              void* d_out, int out_size, void* d_ws, size_t ws_size,
                              hipStream_t stream) {
  const float* enc   = (const float*)d_in[0];   // [B][S][H]
  const float* ehid  = (const float*)d_in[1];   // [1][B][H]
  const int*   tgt   = (const int*)  d_in[2];   // [B][T]
  const float* emb   = (const float*)d_in[3];   // [V][H]
  const float* Wq    = (const float*)d_in[4];
  const float* bq    = (const float*)d_in[5];
  const float* Wk    = (const float*)d_in[6];
  const float* bk    = (const float*)d_in[7];
  const float* Vw    = (const float*)d_in[8];
  const float* bV    = (const float*)d_in[9];
  const float* Wih   = (const float*)d_in[10];  // [4H][2H]
  const float* Whh   = (const float*)d_in[11];  // [4H][H]
  const float* bih   = (const float*)d_in[12];
  const float* bhh   = (const float*)d_in[13];
  const float* Wout  = (const float*)d_in[14];  // [V][H]
  const float* bout  = (const float*)d_in[15];

  float* out  = (float*)d_out;
  float* dec  = out;                          // [B][T][V]
  float* hf   = out + (size_t)B*T*V;
  float* cf   = hf + BH;
  float* attn = cf + BH;                      // [B][T][S]

  float* ws = (float*)d_ws;
  size_t o = 0;
  float* keys  = ws + o; o += (size_t)B*S*H;  // 1,343,488
  float* qbuf  = ws + o; o += BH;
  float* xi    = ws + o; o += (size_t)B*2*H;
  float* gates = ws + o; o += (size_t)B*4*H;
  float* hcur  = ws + o; o += BH;
  float* ccur  = ws + o; o += BH;
  float* hhist = ws + o; o += (size_t)B*T*H;  // total ~11.9 MB

  k_init<<<BH/256, 256, 0, stream>>>(ehid, hcur, ccur);

  // keys_proj = enc @ Wk^T + bk   (M=1312, N=1024, K=1024)
  {
    dim3 grid((B*S + 127)/128, H/128);
    k_gemm<<<grid, 256, 0, stream>>>(enc, Wk, bk, keys, B*S, H, H);
  }

  for (int t = 0; t < T; t++) {
    k_query<<<BH/256, 256, 0, stream>>>(hcur, Wq, bq, qbuf);
    k_attn<<<B, 256, 0, stream>>>(qbuf, keys, enc, Vw, bV, emb, tgt, t, xi, attn);
    k_gates<<<(B*4*H)/256, 256, 0, stream>>>(xi, hcur, Wih, Whh, bih, bhh, gates);
    k_lstm<<<BH/256, 256, 0, stream>>>(gates, hcur, ccur, hhist, t);
  }

  // logits = hhist @ Wout^T + bout  -> straight into d_out rows (row = b*T+t)
  {
    dim3 grid((B*T + 127)/128, V/128);
    k_gemm<<<grid, 256, 0, stream>>>(hhist, Wout, bout, dec, B*T, V, H);
  }
  k_logsm<<<B*T, 256, 0, stream>>>(dec);
  k_copyhc<<<BH/256, 256, 0, stream>>>(hcur, ccur, hf, cf);
}

// Round 2
// 9159.431 us; speedup vs baseline: 1.3001x; 1.3001x over previous
//
#include <hip/hip_runtime.h>
#include <math.h>

#define B 32
#define S 41
#define T 41
#define H 1024
#define V 16384
#define BH (B*H)

__device__ __forceinline__ float fast_sigmoid(float x){ return 1.f/(1.f + __expf(-x)); }
__device__ __forceinline__ float fast_tanh(float x){
  float e = __expf(-2.f*fabsf(x));
  float r = (1.f - e)/(1.f + e);
  return copysignf(r, x);
}

// ---------------- init: h = encoder_hidden[0], c = 0 ----------------
__global__ __launch_bounds__(256) void k_init(const float* __restrict__ eh,
                                              float* __restrict__ h, float* __restrict__ c){
  int i = blockIdx.x*256 + threadIdx.x;
  h[i] = eh[i]; c[i] = 0.f;
}

// ---------------- bsum = bih + bhh ----------------
__global__ __launch_bounds__(256) void k_bsum(const float* __restrict__ a,
                                              const float* __restrict__ b, float* __restrict__ o){
  int i = blockIdx.x*256 + threadIdx.x;
  o[i] = a[i] + b[i];
}

// ---------------- gather teacher-forced embeddings: Xall[t*B+b][:] = emb[tok(t,b)] ----------------
__global__ __launch_bounds__(256) void k_gather(const float* __restrict__ emb,
    const int* __restrict__ tgt, float* __restrict__ Xall){
  int r = blockIdx.x;            // 0..T*B-1
  int t = r / B, b = r % B;
  int tok = (t==0) ? 0 : tgt[b*T + (t-1)];
  const float4* src = (const float4*)(emb + (size_t)tok*H);
  float4* dst = (float4*)(Xall + (size_t)r*H);
  dst[threadIdx.x] = src[threadIdx.x];
}

// ---------------- generic f32 GEMM: C[m][n] = sum_k A[m][k]*W[n*wstride+woff+k] + bias[n] ----------------
// 128x128 tile, BK=16, 256 threads, 8x8 per-thread. N,K multiples of 128/16; M guarded.
__global__ __launch_bounds__(256) void k_gemm(const float* __restrict__ A,
    const float* __restrict__ W, const float* __restrict__ bias,
    float* __restrict__ C, int M, int N, int K, int wstride, int woff)
{
  __shared__ float As[16][128];
  __shared__ float Ws[16][128];
  const int m0 = blockIdx.x*128, n0 = blockIdx.y*128;
  const int tid = threadIdx.x;
  const int r = tid & 127, kq = tid >> 7;          // kq in {0,1}
  const int tm = (tid >> 4)*8, tn = (tid & 15)*8;
  float acc[8][8] = {};
  const float* a_base = A + (size_t)(m0 + r)*K;
  const float* w_base = W + (size_t)(n0 + r)*wstride + woff;
  const bool arow_ok = (m0 + r) < M;
  for (int k0 = 0; k0 < K; k0 += 16) {
    float4 av0 = {0,0,0,0}, av1 = {0,0,0,0};
    if (arow_ok) {
      av0 = *(const float4*)(a_base + k0 + kq*4);
      av1 = *(const float4*)(a_base + k0 + 8 + kq*4);
    }
    float4 wv0 = *(const float4*)(w_base + k0 + kq*4);
    float4 wv1 = *(const float4*)(w_base + k0 + 8 + kq*4);
    __syncthreads();
    {
      int kk = kq*4;
      As[kk+0][r]=av0.x; As[kk+1][r]=av0.y; As[kk+2][r]=av0.z; As[kk+3][r]=av0.w;
      As[kk+8][r]=av1.x; As[kk+9][r]=av1.y; As[kk+10][r]=av1.z; As[kk+11][r]=av1.w;
      Ws[kk+0][r]=wv0.x; Ws[kk+1][r]=wv0.y; Ws[kk+2][r]=wv0.z; Ws[kk+3][r]=wv0.w;
      Ws[kk+8][r]=wv1.x; Ws[kk+9][r]=wv1.y; Ws[kk+10][r]=wv1.z; Ws[kk+11][r]=wv1.w;
    }
    __syncthreads();
    #pragma unroll
    for (int k=0;k<16;k++){
      float a[8], w[8];
      *(float4*)&a[0] = *(const float4*)&As[k][tm];
      *(float4*)&a[4] = *(const float4*)&As[k][tm+4];
      *(float4*)&w[0] = *(const float4*)&Ws[k][tn];
      *(float4*)&w[4] = *(const float4*)&Ws[k][tn+4];
      #pragma unroll
      for (int i=0;i<8;i++)
        #pragma unroll
        for (int j=0;j<8;j++)
          acc[i][j] = fmaf(a[i], w[j], acc[i][j]);
    }
  }
  #pragma unroll
  for (int i=0;i<8;i++){
    int m = m0 + tm + i;
    if (m >= M) break;
    float* crow = C + (size_t)m*N + n0 + tn;
    #pragma unroll
    for (int j=0;j<8;j++) crow[j] = acc[i][j] + bias[n0 + tn + j];
  }
}

// ---------------- per-step skinny GEMM 1: [q | gh] = h @ [Wq ; Whh]^T ----------------
// grid 640 blocks x 256 thr; block handles 8 n-values x 32 b. 8 indep acc chains/thread.
__global__ __launch_bounds__(256) void k_qgh(const float* __restrict__ h,
    const float* __restrict__ Wq, const float* __restrict__ bq,
    const float* __restrict__ Whh, float* __restrict__ q, float* __restrict__ gh)
{
  const int tid = threadIdx.x;
  const int b = tid & 31;
  const int n = blockIdx.x*8 + (tid >> 5);        // 0..5119
  const float* w = (n < H) ? (Wq + (size_t)n*H) : (Whh + (size_t)(n-H)*H);
  const float4* w4 = (const float4*)w;
  const float4* a4 = (const float4*)(h + b*H);
  float4 acc0 = {0,0,0,0}, acc1 = {0,0,0,0};
  #pragma unroll 4
  for (int k = 0; k < H/4; k += 2) {
    float4 a0 = a4[k],   w0 = w4[k];
    float4 a1 = a4[k+1], w1 = w4[k+1];
    acc0.x = fmaf(a0.x,w0.x,acc0.x); acc0.y = fmaf(a0.y,w0.y,acc0.y);
    acc0.z = fmaf(a0.z,w0.z,acc0.z); acc0.w = fmaf(a0.w,w0.w,acc0.w);
    acc1.x = fmaf(a1.x,w1.x,acc1.x); acc1.y = fmaf(a1.y,w1.y,acc1.y);
    acc1.z = fmaf(a1.z,w1.z,acc1.z); acc1.w = fmaf(a1.w,w1.w,acc1.w);
  }
  float s = (acc0.x+acc0.y)+(acc0.z+acc0.w) + (acc1.x+acc1.y)+(acc1.z+acc1.w);
  if (n < H) q[b*H + n] = s + bq[n];
  else       gh[(size_t)b*4*H + (n-H)] = s;
}

// ---------------- per-step skinny GEMM 2: gc = ctx @ Wih[:, H:]^T ----------------
__global__ __launch_bounds__(256) void k_gc(const float* __restrict__ ctx,
    const float* __restrict__ Wih, float* __restrict__ gc)
{
  const int tid = threadIdx.x;
  const int b = tid & 31;
  const int n = blockIdx.x*8 + (tid >> 5);        // 0..4095
  const float4* w4 = (const float4*)(Wih + (size_t)n*2*H + H);
  const float4* a4 = (const float4*)(ctx + b*H);
  float4 acc0 = {0,0,0,0}, acc1 = {0,0,0,0};
  #pragma unroll 4
  for (int k = 0; k < H/4; k += 2) {
    float4 a0 = a4[k],   w0 = w4[k];
    float4 a1 = a4[k+1], w1 = w4[k+1];
    acc0.x = fmaf(a0.x,w0.x,acc0.x); acc0.y = fmaf(a0.y,w0.y,acc0.y);
    acc0.z = fmaf(a0.z,w0.z,acc0.z); acc0.w = fmaf(a0.w,w0.w,acc0.w);
    acc1.x = fmaf(a1.x,w1.x,acc1.x); acc1.y = fmaf(a1.y,w1.y,acc1.y);
    acc1.z = fmaf(a1.z,w1.z,acc1.z); acc1.w = fmaf(a1.w,w1.w,acc1.w);
  }
  float s = (acc0.x+acc0.y)+(acc0.z+acc0.w) + (acc1.x+acc1.y)+(acc1.z+acc1.w);
  gc[(size_t)b*4*H + n] = s;
}

// ---------------- per-step attention: scores (redundant per chunk) -> softmax -> ctx chunk ----------------
// grid: B*4 blocks. block = (b, chunk); chunk owns 256 h-elements of ctx.
__global__ __launch_bounds__(256) void k_attn(
    const float* __restrict__ q,     // [B][H]
    const float* __restrict__ keys,  // [B][S][H]
    const float* __restrict__ enc,   // [B][S][H]
    const float* __restrict__ Vw, const float* __restrict__ bV,
    int t,
    float* __restrict__ ctx,         // [B][H]
    float* __restrict__ attn_out)    // [B][T][S]
{
  const int b = blockIdx.x >> 2;
  const int chunk = blockIdx.x & 3;
  const int tid = threadIdx.x;
  const int lane = tid & 63, wave = tid >> 6;
  __shared__ float w_sh[S];
  __shared__ float w2[S];

  // scores: each wave handles s = wave, wave+4, ... (all 41 per block)
  const float4* q4 = (const float4*)(q + b*H);
  const float4* v4 = (const float4*)Vw;
  for (int s = wave; s < S; s += 4) {
    const float4* k4 = (const float4*)(keys + ((size_t)b*S + s)*H);
    float acc = 0.f;
    #pragma unroll
    for (int j=0;j<4;j++){
      int i = lane + 64*j;
      float4 qv = q4[i], kv = k4[i], vv = v4[i];
      acc += fast_tanh(qv.x+kv.x)*vv.x;
      acc += fast_tanh(qv.y+kv.y)*vv.y;
      acc += fast_tanh(qv.z+kv.z)*vv.z;
      acc += fast_tanh(qv.w+kv.w)*vv.w;
    }
    #pragma unroll
    for (int off=32; off>0; off>>=1) acc += __shfl_down(acc, off);
    if (lane==0) w_sh[s] = acc + bV[0];
  }
  __syncthreads();
  // softmax over 41 entries (wave 0 only), into w2
  if (tid < 64) {
    float val = (tid < S) ? w_sh[tid] : -1e30f;
    float m = val;
    #pragma unroll
    for (int off=32; off>0; off>>=1) m = fmaxf(m, __shfl_xor(m, off));
    float e = (tid < S) ? __expf(val - m) : 0.f;
    float ssum = e;
    #pragma unroll
    for (int off=32; off>0; off>>=1) ssum += __shfl_xor(ssum, off);
    if (tid < S) {
      float w = e / ssum;
      w2[tid] = w;
      if (chunk == 0) attn_out[((size_t)b*T + t)*S + tid] = w;
    }
  }
  __syncthreads();
  // ctx chunk: 256 consecutive h-elements, one per thread
  {
    int hidx = chunk*256 + tid;
    const float* e_base = enc + (size_t)b*S*H + hidx;
    float cx = 0.f;
    #pragma unroll
    for (int s=0;s<S;s++) cx = fmaf(w2[s], e_base[(size_t)s*H], cx);
    ctx[b*H + hidx] = cx;
  }
}

// ---------------- per-step LSTM update: gates = Gx[t] + gh + gc ----------------
__global__ __launch_bounds__(256) void k_lstm(const float* __restrict__ Gx,
    const float* __restrict__ gh, const float* __restrict__ gc,
    float* __restrict__ hcur, float* __restrict__ ccur, float* __restrict__ hhist, int t)
{
  int idx = blockIdx.x*256 + threadIdx.x;  // 32768
  int b = idx >> 10, m = idx & 1023;
  size_t base = (size_t)b*4*H;
  const float* gx = Gx + (size_t)t*B*4*H + base;
  const float* g1 = gh + base;
  const float* g2 = gc + base;
  float vi = gx[m]       + g1[m]       + g2[m];
  float vf = gx[H+m]     + g1[H+m]     + g2[H+m];
  float vg = gx[2*H+m]   + g1[2*H+m]   + g2[2*H+m];
  float vo = gx[3*H+m]   + g1[3*H+m]   + g2[3*H+m];
  float ig = fast_sigmoid(vi);
  float fg = fast_sigmoid(vf);
  float gg = fast_tanh(vg);
  float og = fast_sigmoid(vo);
  float c = fg * ccur[idx] + ig * gg;
  float hn = og * fast_tanh(c);
  ccur[idx] = c;
  hcur[idx] = hn;
  hhist[((size_t)b*T + t)*H + m] = hn;   // row b*T+t matches decoder_outputs row
}

// ---------------- log_softmax in-place over rows of 16384 ----------------
__global__ __launch_bounds__(256) void k_logsm(float* __restrict__ p_all)
{
  float* p = p_all + (size_t)blockIdx.x * V;
  const int tid = threadIdx.x;
  const int lane = tid & 63, wave = tid >> 6;
  __shared__ float red[4];
  float4 v[16];
  float m = -1e30f;
  #pragma unroll
  for (int j=0;j<16;j++){
    v[j] = *(const float4*)(p + 4*(tid + 256*j));
    m = fmaxf(m, fmaxf(fmaxf(v[j].x, v[j].y), fmaxf(v[j].z, v[j].w)));
  }
  #pragma unroll
  for (int off=32; off>0; off>>=1) m = fmaxf(m, __shfl_xor(m, off));
  if (lane==0) red[wave] = m;
  __syncthreads();
  m = fmaxf(fmaxf(red[0], red[1]), fmaxf(red[2], red[3]));
  float ssum = 0.f;
  #pragma unroll
  for (int j=0;j<16;j++){
    ssum += __expf(v[j].x - m) + __expf(v[j].y - m) + __expf(v[j].z - m) + __expf(v[j].w - m);
  }
  #pragma unroll
  for (int off=32; off>0; off>>=1) ssum += __shfl_xor(ssum, off);
  __syncthreads();
  if (lane==0) red[wave] = ssum;
  __syncthreads();
  float lse = m + __logf(red[0] + red[1] + red[2] + red[3]);
  #pragma unroll
  for (int j=0;j<16;j++){
    float4 o; o.x = v[j].x - lse; o.y = v[j].y - lse; o.z = v[j].z - lse; o.w = v[j].w - lse;
    *(float4*)(p + 4*(tid + 256*j)) = o;
  }
}

// ---------------- final h/c copy ----------------
__global__ __launch_bounds__(256) void k_copyhc(const float* __restrict__ h, const float* __restrict__ c,
                                                float* __restrict__ oh, float* __restrict__ oc)
{
  int i = blockIdx.x*256 + threadIdx.x;
  oh[i] = h[i]; oc[i] = c[i];
}

extern "C" void kernel_launch(void* const* d_in, const int* in_sizes, int n_in,
                              void* d_out, int out_size, void* d_ws, size_t ws_size,
                              hipStream_t stream) {
  const float* enc   = (const float*)d_in[0];   // [B][S][H]
  const float* ehid  = (const float*)d_in[1];   // [1][B][H]
  const int*   tgt   = (const int*)  d_in[2];   // [B][T]
  const float* emb   = (const float*)d_in[3];   // [V][H]
  const float* Wq    = (const float*)d_in[4];
  const float* bq    = (const float*)d_in[5];
  const float* Wk    = (const float*)d_in[6];
  const float* bk    = (const float*)d_in[7];
  const float* Vw    = (const float*)d_in[8];
  const float* bV    = (const float*)d_in[9];
  const float* Wih   = (const float*)d_in[10];  // [4H][2H]
  const float* Whh   = (const float*)d_in[11];  // [4H][H]
  const float* bih   = (const float*)d_in[12];
  const float* bhh   = (const float*)d_in[13];
  const float* Wout  = (const float*)d_in[14];  // [V][H]
  const float* bout  = (const float*)d_in[15];

  float* out  = (float*)d_out;
  float* dec  = out;                          // [B][T][V]
  float* hf   = out + (size_t)B*T*V;
  float* cf   = hf + BH;
  float* attn = cf + BH;                      // [B][T][S]

  float* ws = (float*)d_ws;
  size_t o = 0;
  float* keys  = ws + o; o += (size_t)B*S*H;    // 1.34M
  float* hhist = ws + o; o += (size_t)B*T*H;    // 1.34M (doubles as Xall: consumed before loop)
  float* Gx    = ws + o; o += (size_t)T*B*4*H;  // 5.37M
  float* qbuf  = ws + o; o += BH;
  float* ghbuf = ws + o; o += (size_t)B*4*H;
  float* gcbuf = ws + o; o += (size_t)B*4*H;
  float* ctx   = ws + o; o += BH;
  float* hcur  = ws + o; o += BH;
  float* ccur  = ws + o; o += BH;
  float* bsum  = ws + o; o += 4*H;
  float* Xall  = hhist;                         // alias: Xall dead before hhist written

  k_init<<<BH/256, 256, 0, stream>>>(ehid, hcur, ccur);
  k_bsum<<<(4*H)/256, 256, 0, stream>>>(bih, bhh, bsum);
  k_gather<<<T*B, 256, 0, stream>>>(emb, tgt, Xall);

  // keys_proj = enc @ Wk^T + bk   (M=1312, N=1024, K=1024)
  {
    dim3 grid((B*S + 127)/128, H/128);
    k_gemm<<<grid, 256, 0, stream>>>(enc, Wk, bk, keys, B*S, H, H, H, 0);
  }
  // Gx = Xall @ Wih[:, :H]^T + (bih+bhh)   (M=1312, N=4096, K=1024)
  {
    dim3 grid((T*B + 127)/128, (4*H)/128);
    k_gemm<<<grid, 256, 0, stream>>>(Xall, Wih, bsum, Gx, T*B, 4*H, H, 2*H, 0);
  }

  for (int t = 0; t < T; t++) {
    k_qgh <<<(5*H)/8, 256, 0, stream>>>(hcur, Wq, bq, Whh, qbuf, ghbuf);
    k_attn<<<B*4, 256, 0, stream>>>(qbuf, keys, enc, Vw, bV, t, ctx, attn);
    k_gc  <<<(4*H)/8, 256, 0, stream>>>(ctx, Wih, gcbuf);
    k_lstm<<<BH/256, 256, 0, stream>>>(Gx, ghbuf, gcbuf, hcur, ccur, hhist, t);
  }

  // logits = hhist @ Wout^T + bout  -> straight into d_out rows (row = b*T+t)
  {
    dim3 grid((B*T + 127)/128, V/128);
    k_gemm<<<grid, 256, 0, stream>>>(hhist, Wout, bout, dec, B*T, V, H, H, 0);
  }
  k_logsm<<<B*T, 256, 0, stream>>>(dec);
  k_copyhc<<<BH/256, 256, 0, stream>>>(hcur, ccur, hf, cf);
}